// Round 6
// baseline (337.190 us; speedup 1.0000x reference)
//
#include <hip/hip_runtime.h>

#define NPG    50
#define HF     128
#define FDIM   64
#define NGRAPH 2048
#define NNODES 102400
#define EPG    400
#define SP     72     // featT row stride (bf16): 144B, 16B-aligned
#define CS2    33     // cnt row stride (ints): odd -> conflict-free column gather

typedef __attribute__((ext_vector_type(8))) short bf16x8;
typedef __attribute__((ext_vector_type(4))) float floatx4;

__device__ __forceinline__ float leaky(float x, float s) { return x >= 0.f ? x : x * s; }
__device__ __forceinline__ unsigned short f2bf(float f) {   // RNE fp32->bf16
    unsigned u = __float_as_uint(f);
    return (unsigned short)((u + 0x7fffu + ((u >> 16) & 1u)) >> 16);
}
__device__ __forceinline__ float bf2f(unsigned short h) {
    return __uint_as_float(((unsigned)h) << 16);
}
__device__ __forceinline__ int fkey(float f) { int b = __float_as_int(f); return b >= 0 ? b : b ^ 0x7fffffff; }
__device__ __forceinline__ float funkey(int k) { return __int_as_float(k >= 0 ? k : k ^ 0x7fffffff); }

// Build transposed bf16 weights: wt0[256][64] = [W0|resW0]^T, wt1/wt2[128][128] = W^T
__global__ void prep_w(const float* __restrict__ W0, const float* __restrict__ rW0,
                       const float* __restrict__ W1, const float* __restrict__ W2,
                       unsigned short* __restrict__ wt0, unsigned short* __restrict__ wt1,
                       unsigned short* __restrict__ wt2) {
    int i = blockIdx.x * 256 + threadIdx.x;
    if (i < 256 * 64) {
        int n = i >> 6, k = i & 63;
        float v = (n < 128) ? W0[k * 128 + n] : rW0[k * 128 + (n - 128)];
        wt0[i] = f2bf(v);
    }
    if (i < 128 * 128) {
        int n = i >> 7, k = i & 127;
        wt1[i] = f2bf(W1[k * 128 + n]);
        wt2[i] = f2bf(W2[k * 128 + n]);
    }
}

// RESW (layer0): hin is fp32 [N,64]; else hin is packed bf16 [N,128].
template <int K, bool RESW, bool WRITE_H>
__global__ __launch_bounds__(512, 8) void layer_kernel(
    const void* __restrict__ hin_, const unsigned short* __restrict__ Wt,
    const float* __restrict__ al, const float* __restrict__ ar,
    const float* __restrict__ gw, const float* __restrict__ bw,
    const int* __restrict__ src, const int* __restrict__ dst,
    unsigned short* __restrict__ hout, float* __restrict__ out, int layer)
{
    __shared__ unsigned short featT[HF * SP];       // 18432 B  bf16 feat^T [col][node]
    __shared__ int cnt[NPG * CS2];                  // 6600 B
    __shared__ float res_s[RESW ? NPG * HF : 1];    // 25600 B (layer0 only)
    __shared__ float el_s[128], er_s[128], rden_s[128];
    __shared__ int elmax_i[2];
    __shared__ float musum[64], sqsum[64], psum[HF], gb_s[2 * HF];

    const float* hinf = (const float*)hin_;
    const unsigned short* hinb = (const unsigned short*)hin_;

    const int g = blockIdx.x, t = threadIdx.x;
    const int nbase = g * NPG;
    const int w = t >> 6, lane = t & 63, quad = lane >> 4, l16 = lane & 15;

    // early edge loads
    int es = 0, ed = 0;
    if (t < EPG) { es = src[g * EPG + t] - nbase; ed = dst[g * EPG + t] - nbase; }

    // ---- P0: zero / stage ----
    for (int i = t; i < NPG * CS2; i += 512) cnt[i] = 0;
    if (t < 64) { musum[t] = 0.f; sqsum[t] = 0.f; }
    if (t < HF) { psum[t] = 0.f; gb_s[t] = gw[t]; gb_s[HF + t] = bw[t]; }
    if (t < 2) elmax_i[t] = (int)0x80000000;
    __syncthreads();

    if (t < EPG) atomicAdd(&cnt[ed * CS2 + (es >> 1)], 1 << ((es & 1) * 16));
    if (t < NPG) atomicAdd(&cnt[t * CS2 + (t >> 1)], 1 << ((t & 1) * 16));

    // ---- P1: GEMM via MFMA + el/er + elmax + featT/res stores ----
    constexpr int KS = K / 32;
    constexpr int NT = RESW ? 8 : 4;
    const int mt = w & 3;
    const int ntbase = (w >> 2) * NT;

    int mrow = mt * 16 + l16;
    if (mrow >= NPG) mrow = NPG - 1;
    bf16x8 afr[KS];
    if constexpr (RESW) {
        const float* hrow = hinf + (size_t)(nbase + mrow) * K;
#pragma unroll
        for (int ks = 0; ks < KS; ++ks) {
            int k0 = ks * 32 + quad * 8;
            float4 p0 = *(const float4*)(hrow + k0);
            float4 p1 = *(const float4*)(hrow + k0 + 4);
            bf16x8 a;
            a[0] = (short)f2bf(p0.x); a[1] = (short)f2bf(p0.y);
            a[2] = (short)f2bf(p0.z); a[3] = (short)f2bf(p0.w);
            a[4] = (short)f2bf(p1.x); a[5] = (short)f2bf(p1.y);
            a[6] = (short)f2bf(p1.z); a[7] = (short)f2bf(p1.w);
            afr[ks] = a;
        }
    } else {
        const unsigned short* hrow = hinb + (size_t)(nbase + mrow) * K;
#pragma unroll
        for (int ks = 0; ks < KS; ++ks)
            afr[ks] = *(const bf16x8*)(hrow + ks * 32 + quad * 8);
    }

    floatx4 acc[NT];
    const floatx4 zf = {0.f, 0.f, 0.f, 0.f};
#pragma unroll
    for (int nt = 0; nt < NT; ++nt) acc[nt] = zf;
#pragma unroll
    for (int nt = 0; nt < NT; ++nt) {
        const unsigned short* wrow = Wt + (size_t)((ntbase + nt) * 16 + l16) * K;
#pragma unroll
        for (int ks = 0; ks < KS; ++ks) {
            bf16x8 b = *(const bf16x8*)(wrow + ks * 32 + quad * 8);
            acc[nt] = __builtin_amdgcn_mfma_f32_16x16x32_bf16(afr[ks], b, acc[nt], 0, 0, 0);
        }
    }

    // el/er from fp32 acc: butterfly over l16 lanes; elmax via LDS atomicMax.
    if (!RESW || w < 4) {
        float pe0[4] = {0,0,0,0}, pr0[4] = {0,0,0,0};
        float pe1[4] = {0,0,0,0}, pr1[4] = {0,0,0,0};
#pragma unroll
        for (int nt = 0; nt < NT; ++nt) {
            int col = (ntbase + nt) * 16 + l16;
            if (RESW && col >= HF) continue;
            float av = al[col], rv = ar[col];
            bool second = RESW && (nt >= 4);
#pragma unroll
            for (int r = 0; r < 4; ++r) {
                float x = acc[nt][r];
                if (second) { pe1[r] = fmaf(x, av, pe1[r]); pr1[r] = fmaf(x, rv, pr1[r]); }
                else        { pe0[r] = fmaf(x, av, pe0[r]); pr0[r] = fmaf(x, rv, pr0[r]); }
            }
        }
#pragma unroll
        for (int m = 1; m <= 8; m <<= 1) {
#pragma unroll
            for (int r = 0; r < 4; ++r) {
                pe0[r] += __shfl_xor(pe0[r], m, 64);
                pr0[r] += __shfl_xor(pr0[r], m, 64);
                if (RESW) { pe1[r] += __shfl_xor(pe1[r], m, 64);
                            pr1[r] += __shfl_xor(pr1[r], m, 64); }
            }
        }
        if (l16 == 0) {
#pragma unroll
            for (int r = 0; r < 4; ++r) {
                int row = mt * 16 + quad * 4 + r;
                if (RESW) {
                    el_s[row] = pe0[r];      er_s[row] = pr0[r];
                    el_s[64 + row] = pe1[r]; er_s[64 + row] = pr1[r];
                    atomicMax(&elmax_i[0], fkey(pe0[r]));
                    atomicMax(&elmax_i[1], fkey(pe1[r]));
                } else {
                    int hd = w >> 2;
                    el_s[hd * 64 + row] = pe0[r];
                    er_s[hd * 64 + row] = pr0[r];
                    atomicMax(&elmax_i[hd], fkey(pe0[r]));
                }
            }
        }
    }

    // featT stores (b64-packed) / res stores (L0 high cols)
#pragma unroll
    for (int nt = 0; nt < NT; ++nt) {
        int n = (ntbase + nt) * 16 + l16;
        if (!RESW || n < HF) {
            unsigned lo = (unsigned)f2bf(acc[nt][0]) | ((unsigned)f2bf(acc[nt][1]) << 16);
            unsigned hi = (unsigned)f2bf(acc[nt][2]) | ((unsigned)f2bf(acc[nt][3]) << 16);
            uint2 pk = {lo, hi};
            *(uint2*)&featT[n * SP + mt * 16 + quad * 4] = pk;
        } else {
#pragma unroll
            for (int r = 0; r < 4; ++r) {
                int d = mt * 16 + quad * 4 + r;
                if (d < NPG) res_s[d * HF + (n - HF)] = acc[nt][r];
            }
        }
    }
    __syncthreads();

    // ---- P3: A-frag exp build + aggregation MFMA + LN stats + direct epilogue ----
    const int hd = w >> 2, amt = w & 3;
    const int d = amt * 16 + l16;   // this lane's A-frag dst row

    // prefetch residual (layers 1/2) early: bf16 h
    float resid[4][4];
    if (!RESW) {
#pragma unroll
        for (int nt = 0; nt < 4; ++nt)
#pragma unroll
            for (int r = 0; r < 4; ++r) {
                int dd = amt * 16 + quad * 4 + r;
                if (dd >= NPG) dd = NPG - 1;
                resid[nt][r] = bf2f(hinb[(size_t)(nbase + dd) * K + hd * 64 + nt * 16 + l16]);
            }
    }

    float erd = (d < NPG) ? er_s[hd * 64 + d] : 0.f;
    float md = leaky(funkey(elmax_i[hd]) + erd, 0.2f);
    bf16x8 ap[2];
    float rowsum = 0.f;
#pragma unroll
    for (int ks = 0; ks < 2; ++ks) {
        bf16x8 a;
#pragma unroll
        for (int j = 0; j < 8; ++j) {
            int s = ks * 32 + quad * 8 + j;
            float x = 0.f;
            if (d < NPG && s < NPG) {
                int c = (cnt[d * CS2 + (s >> 1)] >> ((s & 1) * 16)) & 0xffff;
                if (c) x = (float)c * __expf(leaky(el_s[hd * 64 + s] + erd, 0.2f) - md);
            }
            unsigned short xb = f2bf(x);
            a[j] = (short)xb;
            rowsum += bf2f(xb);
        }
        ap[ks] = a;
    }
    rowsum += __shfl_xor(rowsum, 16, 64);
    rowsum += __shfl_xor(rowsum, 32, 64);
    if (quad == 0) rden_s[hd * 64 + d] = 1.f / fmaxf(rowsum, 1e-30f);

    floatx4 ag[4];
#pragma unroll
    for (int nt = 0; nt < 4; ++nt) ag[nt] = zf;
#pragma unroll
    for (int nt = 0; nt < 4; ++nt) {
        const unsigned short* fr = &featT[(hd * 64 + nt * 16 + l16) * SP];
#pragma unroll
        for (int ks = 0; ks < 2; ++ks) {
            bf16x8 b = *(const bf16x8*)(fr + ks * 32 + quad * 8);
            ag[nt] = __builtin_amdgcn_mfma_f32_16x16x32_bf16(ap[ks], b, ag[nt], 0, 0, 0);
        }
    }

    // scale + residual; LN partial sums (no rst LDS round-trip)
    float vals[4][4];
    float s1[4] = {0,0,0,0}, s2[4] = {0,0,0,0};
#pragma unroll
    for (int nt = 0; nt < 4; ++nt) {
#pragma unroll
        for (int r = 0; r < 4; ++r) {
            int dd = amt * 16 + quad * 4 + r;
            float rdv = rden_s[hd * 64 + (dd < 64 ? dd : 63)];
            float rv;
            if (RESW) rv = (dd < NPG) ? res_s[dd * HF + hd * 64 + nt * 16 + l16] : 0.f;
            else rv = resid[nt][r];
            float vv = ag[nt][r] * rdv + rv;
            vals[nt][r] = vv;
            s1[r] += vv;
            s2[r] = fmaf(vv, vv, s2[r]);
        }
    }
#pragma unroll
    for (int m = 1; m <= 8; m <<= 1) {
#pragma unroll
        for (int r = 0; r < 4; ++r) {
            s1[r] += __shfl_xor(s1[r], m, 64);
            s2[r] += __shfl_xor(s2[r], m, 64);
        }
    }
    if (l16 == 0) {
#pragma unroll
        for (int r = 0; r < 4; ++r) {
            int dd = amt * 16 + quad * 4 + r;
            if (dd < NPG) { atomicAdd(&musum[dd], s1[r]); atomicAdd(&sqsum[dd], s2[r]); }
        }
    }
    __syncthreads();

    // normalize + affine + leaky from registers; write bf16 h; readout partials
    float part[4] = {0, 0, 0, 0};
#pragma unroll
    for (int nt = 0; nt < 4; ++nt) {
        int col = hd * 64 + nt * 16 + l16;
        float gq = gb_s[col], bq = gb_s[HF + col];
#pragma unroll
        for (int r = 0; r < 4; ++r) {
            int dd = amt * 16 + quad * 4 + r;
            if (dd < NPG) {
                float mu = musum[dd] * (1.f / HF);
                float rs = rsqrtf(sqsum[dd] * (1.f / HF) - mu * mu + 1e-5f);
                float y = (vals[nt][r] - mu) * rs * gq + bq;
                y = leaky(y, 0.1f);
                if (WRITE_H) hout[(size_t)(nbase + dd) * HF + col] = f2bf(y);
                part[nt] += y;
            }
        }
    }
#pragma unroll
    for (int nt = 0; nt < 4; ++nt)
        atomicAdd(&psum[hd * 64 + nt * 16 + l16], part[nt]);
    __syncthreads();

    if (t < FDIM) {
        float s = (psum[t] + psum[t + FDIM]) * (1.f / (2 * NPG));
        out[(size_t)g * (3 * FDIM) + layer * FDIM + t] = leaky(s, 0.1f);
    }
}

extern "C" void kernel_launch(void* const* d_in, const int* in_sizes, int n_in,
                              void* d_out, int out_size, void* d_ws, size_t ws_size,
                              hipStream_t stream) {
    const float* x   = (const float*)d_in[0];
    const float* W0  = (const float*)d_in[1];
    const float* al0 = (const float*)d_in[2];
    const float* ar0 = (const float*)d_in[3];
    const float* rW0 = (const float*)d_in[4];
    const float* g0  = (const float*)d_in[5];
    const float* b0  = (const float*)d_in[6];
    const float* W1  = (const float*)d_in[7];
    const float* al1 = (const float*)d_in[8];
    const float* ar1 = (const float*)d_in[9];
    const float* g1  = (const float*)d_in[10];
    const float* b1  = (const float*)d_in[11];
    const float* W2  = (const float*)d_in[12];
    const float* al2 = (const float*)d_in[13];
    const float* ar2 = (const float*)d_in[14];
    const float* g2  = (const float*)d_in[15];
    const float* b2  = (const float*)d_in[16];
    const int* src   = (const int*)d_in[17];
    const int* dst   = (const int*)d_in[18];
    float* out = (float*)d_out;

    char* ws = (char*)d_ws;
    unsigned short* bufA = (unsigned short*)ws;                       // h1 [N,128] bf16
    unsigned short* bufB = bufA + (size_t)NNODES * HF;                // h2 [N,128] bf16
    unsigned short* wt0  = bufB + (size_t)NNODES * HF;
    unsigned short* wt1  = wt0 + 256 * 64;
    unsigned short* wt2  = wt1 + 128 * 128;

    prep_w<<<64, 256, 0, stream>>>(W0, rW0, W1, W2, wt0, wt1, wt2);

    layer_kernel<64, true, true><<<NGRAPH, 512, 0, stream>>>(
        x, wt0, al0, ar0, g0, b0, src, dst, bufA, out, 0);
    layer_kernel<128, false, true><<<NGRAPH, 512, 0, stream>>>(
        bufA, wt1, al1, ar1, g1, b1, src, dst, bufB, out, 1);
    layer_kernel<128, false, false><<<NGRAPH, 512, 0, stream>>>(
        bufB, wt2, al2, ar2, g2, b2, src, dst, nullptr, out, 2);
}

// Round 7
// 313.878 us; speedup vs baseline: 1.0743x; 1.0743x over previous
//
#include <hip/hip_runtime.h>

#define NPG    50
#define HF     128
#define FDIM   64
#define NGRAPH 2048
#define NNODES 102400
#define EPG    400
#define SP     72     // featT row stride (bf16): 144B, 16B-aligned
#define CS4    13     // cnt row stride (ints): 4 8-bit counts per int
#define HB     136    // hbuf row stride (bf16): 272B, 16B-aligned

typedef __attribute__((ext_vector_type(8))) short bf16x8;
typedef __attribute__((ext_vector_type(4))) float floatx4;

__device__ __forceinline__ float leaky(float x, float s) { return x >= 0.f ? x : x * s; }
__device__ __forceinline__ unsigned short f2bf(float f) {   // RNE fp32->bf16
    unsigned u = __float_as_uint(f);
    return (unsigned short)((u + 0x7fffu + ((u >> 16) & 1u)) >> 16);
}
__device__ __forceinline__ float bf2f(unsigned short h) {
    return __uint_as_float(((unsigned)h) << 16);
}
__device__ __forceinline__ int fkey(float f) { int b = __float_as_int(f); return b >= 0 ? b : b ^ 0x7fffffff; }
__device__ __forceinline__ float funkey(int k) { return __int_as_float(k >= 0 ? k : k ^ 0x7fffffff); }

// Build transposed bf16 weights: wt0[256][64] = [W0|resW0]^T, wt1/wt2[128][128] = W^T
__global__ void prep_w(const float* __restrict__ W0, const float* __restrict__ rW0,
                       const float* __restrict__ W1, const float* __restrict__ W2,
                       unsigned short* __restrict__ wt0, unsigned short* __restrict__ wt1,
                       unsigned short* __restrict__ wt2) {
    int i = blockIdx.x * 256 + threadIdx.x;
    if (i < 256 * 64) {
        int n = i >> 6, k = i & 63;
        float v = (n < 128) ? W0[k * 128 + n] : rW0[k * 128 + (n - 128)];
        wt0[i] = f2bf(v);
    }
    if (i < 128 * 128) {
        int n = i >> 7, k = i & 127;
        wt1[i] = f2bf(W1[k * 128 + n]);
        wt2[i] = f2bf(W2[k * 128 + n]);
    }
}

// RESW (layer0): hin is fp32 [N,64]; else hin is packed bf16 [N,128].
template <int K, bool RESW, bool WRITE_H>
__global__ __launch_bounds__(512, 8) void layer_kernel(
    const void* __restrict__ hin_, const unsigned short* __restrict__ Wt,
    const float* __restrict__ al, const float* __restrict__ ar,
    const float* __restrict__ gw, const float* __restrict__ bw,
    const int* __restrict__ src, const int* __restrict__ dst,
    unsigned short* __restrict__ hout, float* __restrict__ out, int layer)
{
    __shared__ unsigned short featT[HF * SP];       // 18432 B; reused as ybuf[50][128]
    __shared__ int cnt[NPG * CS4];                  // 2600 B
    __shared__ unsigned short hres[NPG * HB];       // 13600 B: L0 res_b[50][128]; L1/2 hbuf[50][HB]
    __shared__ float el_s[128], er_s[128], rden_s[128];
    __shared__ int elmax_i[2];
    __shared__ float musum[64], sqsum[64], psum[HF], gb_s[2 * HF];

    const float* hinf = (const float*)hin_;
    const unsigned short* hinb = (const unsigned short*)hin_;
    unsigned short* ybuf = featT;   // alias: featT dead after aggregation MFMA

    const int g = blockIdx.x, t = threadIdx.x;
    const int nbase = g * NPG;
    const int w = t >> 6, lane = t & 63, quad = lane >> 4, l16 = lane & 15;

    // early edge loads
    int es = 0, ed = 0;
    if (t < EPG) { es = src[g * EPG + t] - nbase; ed = dst[g * EPG + t] - nbase; }

    // ---- P0: zero / stage ----
    for (int i = t; i < NPG * CS4; i += 512) cnt[i] = 0;
    if (t < 64) { musum[t] = 0.f; sqsum[t] = 0.f; }
    if (t < HF) { psum[t] = 0.f; gb_s[t] = gw[t]; gb_s[HF + t] = bw[t]; }
    if (t < 2) elmax_i[t] = (int)0x80000000;
    if constexpr (!RESW) {   // stage h block (bf16) into hbuf, coalesced
        for (int i = t; i < 800; i += 512) {
            int row = i >> 4, c = i & 15;
            *(uint4*)&hres[row * HB + c * 8] =
                *(const uint4*)&hinb[(size_t)(nbase + row) * HF + c * 8];
        }
    }
    __syncthreads();

    if (t < EPG) atomicAdd(&cnt[ed * CS4 + (es >> 2)], 1 << ((es & 3) * 8));
    if (t < NPG) atomicAdd(&cnt[t * CS4 + (t >> 2)], 1 << ((t & 3) * 8));

    // ---- P1: GEMM via MFMA + el/er + elmax + featT/res stores ----
    constexpr int KS = K / 32;
    constexpr int NT = RESW ? 8 : 4;
    const int mt = w & 3;
    const int ntbase = (w >> 2) * NT;

    int mrow = mt * 16 + l16;
    if (mrow >= NPG) mrow = NPG - 1;
    bf16x8 afr[KS];
    if constexpr (RESW) {
        const float* hrow = hinf + (size_t)(nbase + mrow) * K;
#pragma unroll
        for (int ks = 0; ks < KS; ++ks) {
            int k0 = ks * 32 + quad * 8;
            float4 p0 = *(const float4*)(hrow + k0);
            float4 p1 = *(const float4*)(hrow + k0 + 4);
            bf16x8 a;
            a[0] = (short)f2bf(p0.x); a[1] = (short)f2bf(p0.y);
            a[2] = (short)f2bf(p0.z); a[3] = (short)f2bf(p0.w);
            a[4] = (short)f2bf(p1.x); a[5] = (short)f2bf(p1.y);
            a[6] = (short)f2bf(p1.z); a[7] = (short)f2bf(p1.w);
            afr[ks] = a;
        }
    } else {
#pragma unroll
        for (int ks = 0; ks < KS; ++ks)
            afr[ks] = *(const bf16x8*)&hres[mrow * HB + ks * 32 + quad * 8];
    }

    floatx4 acc[NT];
    const floatx4 zf = {0.f, 0.f, 0.f, 0.f};
#pragma unroll
    for (int nt = 0; nt < NT; ++nt) acc[nt] = zf;
#pragma unroll
    for (int nt = 0; nt < NT; ++nt) {
        const unsigned short* wrow = Wt + (size_t)((ntbase + nt) * 16 + l16) * K;
#pragma unroll
        for (int ks = 0; ks < KS; ++ks) {
            bf16x8 b = *(const bf16x8*)(wrow + ks * 32 + quad * 8);
            acc[nt] = __builtin_amdgcn_mfma_f32_16x16x32_bf16(afr[ks], b, acc[nt], 0, 0, 0);
        }
    }

    // el/er from fp32 acc: butterfly over l16 lanes; elmax via LDS atomicMax.
    if (!RESW || w < 4) {
        float pe0[4] = {0,0,0,0}, pr0[4] = {0,0,0,0};
        float pe1[4] = {0,0,0,0}, pr1[4] = {0,0,0,0};
#pragma unroll
        for (int nt = 0; nt < NT; ++nt) {
            int col = (ntbase + nt) * 16 + l16;
            if (RESW && col >= HF) continue;
            float av = al[col], rv = ar[col];
            bool second = RESW && (nt >= 4);
#pragma unroll
            for (int r = 0; r < 4; ++r) {
                float x = acc[nt][r];
                if (second) { pe1[r] = fmaf(x, av, pe1[r]); pr1[r] = fmaf(x, rv, pr1[r]); }
                else        { pe0[r] = fmaf(x, av, pe0[r]); pr0[r] = fmaf(x, rv, pr0[r]); }
            }
        }
#pragma unroll
        for (int m = 1; m <= 8; m <<= 1) {
#pragma unroll
            for (int r = 0; r < 4; ++r) {
                pe0[r] += __shfl_xor(pe0[r], m, 64);
                pr0[r] += __shfl_xor(pr0[r], m, 64);
                if (RESW) { pe1[r] += __shfl_xor(pe1[r], m, 64);
                            pr1[r] += __shfl_xor(pr1[r], m, 64); }
            }
        }
        if (l16 == 0) {
#pragma unroll
            for (int r = 0; r < 4; ++r) {
                int row = mt * 16 + quad * 4 + r;
                if (RESW) {
                    el_s[row] = pe0[r];      er_s[row] = pr0[r];
                    el_s[64 + row] = pe1[r]; er_s[64 + row] = pr1[r];
                    atomicMax(&elmax_i[0], fkey(pe0[r]));
                    atomicMax(&elmax_i[1], fkey(pe1[r]));
                } else {
                    int hd = w >> 2;
                    el_s[hd * 64 + row] = pe0[r];
                    er_s[hd * 64 + row] = pr0[r];
                    atomicMax(&elmax_i[hd], fkey(pe0[r]));
                }
            }
        }
    }

    // featT stores (b64-packed) / res stores bf16 (L0 high cols, stride 128)
#pragma unroll
    for (int nt = 0; nt < NT; ++nt) {
        int n = (ntbase + nt) * 16 + l16;
        if (!RESW || n < HF) {
            unsigned lo = (unsigned)f2bf(acc[nt][0]) | ((unsigned)f2bf(acc[nt][1]) << 16);
            unsigned hi = (unsigned)f2bf(acc[nt][2]) | ((unsigned)f2bf(acc[nt][3]) << 16);
            uint2 pk = {lo, hi};
            *(uint2*)&featT[n * SP + mt * 16 + quad * 4] = pk;
        } else {
#pragma unroll
            for (int r = 0; r < 4; ++r) {
                int d = mt * 16 + quad * 4 + r;
                if (d < NPG) hres[d * HF + (n - HF)] = f2bf(acc[nt][r]);
            }
        }
    }
    __syncthreads();

    // ---- P3: A-frag exp build + aggregation MFMA + LN stats ----
    const int hd = w >> 2, amt = w & 3;
    const int d = amt * 16 + l16;   // this lane's A-frag dst row

    float erd = (d < NPG) ? er_s[hd * 64 + d] : 0.f;
    float md = leaky(funkey(elmax_i[hd]) + erd, 0.2f);
    bf16x8 ap[2];
    float rowsum = 0.f;
#pragma unroll
    for (int ks = 0; ks < 2; ++ks) {
        bf16x8 a;
#pragma unroll
        for (int j = 0; j < 8; ++j) {
            int s = ks * 32 + quad * 8 + j;
            float x = 0.f;
            if (d < NPG && s < NPG) {
                int c = (cnt[d * CS4 + (s >> 2)] >> ((s & 3) * 8)) & 0xff;
                if (c) x = (float)c * __expf(leaky(el_s[hd * 64 + s] + erd, 0.2f) - md);
            }
            unsigned short xb = f2bf(x);
            a[j] = (short)xb;
            rowsum += bf2f(xb);
        }
        ap[ks] = a;
    }
    rowsum += __shfl_xor(rowsum, 16, 64);
    rowsum += __shfl_xor(rowsum, 32, 64);
    if (quad == 0) rden_s[hd * 64 + d] = 1.f / fmaxf(rowsum, 1e-30f);

    floatx4 ag[4];
#pragma unroll
    for (int nt = 0; nt < 4; ++nt) ag[nt] = zf;
#pragma unroll
    for (int nt = 0; nt < 4; ++nt) {
        const unsigned short* fr = &featT[(hd * 64 + nt * 16 + l16) * SP];
#pragma unroll
        for (int ks = 0; ks < 2; ++ks) {
            bf16x8 b = *(const bf16x8*)(fr + ks * 32 + quad * 8);
            ag[nt] = __builtin_amdgcn_mfma_f32_16x16x32_bf16(ap[ks], b, ag[nt], 0, 0, 0);
        }
    }

    // scale + residual (from LDS: L0 res_b stride HF, L1/2 hbuf stride HB); LN partials
    float vals[4][4];
    float s1[4] = {0,0,0,0}, s2[4] = {0,0,0,0};
#pragma unroll
    for (int nt = 0; nt < 4; ++nt) {
#pragma unroll
        for (int r = 0; r < 4; ++r) {
            int dd = amt * 16 + quad * 4 + r;
            float rdv = rden_s[hd * 64 + (dd < 64 ? dd : 63)];
            int col = hd * 64 + nt * 16 + l16;
            int dc = dd < NPG ? dd : NPG - 1;
            float rv = RESW ? bf2f(hres[dc * HF + col]) : bf2f(hres[dc * HB + col]);
            float vv = ag[nt][r] * rdv + rv;
            vals[nt][r] = vv;
            s1[r] += vv;
            s2[r] = fmaf(vv, vv, s2[r]);
        }
    }
#pragma unroll
    for (int m = 1; m <= 8; m <<= 1) {
#pragma unroll
        for (int r = 0; r < 4; ++r) {
            s1[r] += __shfl_xor(s1[r], m, 64);
            s2[r] += __shfl_xor(s2[r], m, 64);
        }
    }
    if (l16 == 0) {
#pragma unroll
        for (int r = 0; r < 4; ++r) {
            int dd = amt * 16 + quad * 4 + r;
            if (dd < NPG) { atomicAdd(&musum[dd], s1[r]); atomicAdd(&sqsum[dd], s2[r]); }
        }
    }
    __syncthreads();   // LN stats complete; featT reads complete -> ybuf may overwrite

    // normalize + affine + leaky from registers -> ybuf (bf16, hout image)
#pragma unroll
    for (int nt = 0; nt < 4; ++nt) {
        int col = hd * 64 + nt * 16 + l16;
        float gq = gb_s[col], bq = gb_s[HF + col];
#pragma unroll
        for (int r = 0; r < 4; ++r) {
            int dd = amt * 16 + quad * 4 + r;
            if (dd < NPG) {
                float mu = musum[dd] * (1.f / HF);
                float rs = rsqrtf(sqsum[dd] * (1.f / HF) - mu * mu + 1e-5f);
                float y = (vals[nt][r] - mu) * rs * gq + bq;
                ybuf[dd * HF + col] = f2bf(leaky(y, 0.1f));
            }
        }
    }
    __syncthreads();

    // ---- P4: coalesced h store + readout ----
    if constexpr (WRITE_H) {
        for (int i = t; i < 800; i += 512)
            *(uint4*)&hout[(size_t)nbase * HF + i * 8] = *(const uint4*)&ybuf[i * 8];
    }
    {
        const int c = t & 127, g4 = t >> 7;
        float part = 0.f;
        for (int n = g4; n < NPG; n += 4) part += bf2f(ybuf[n * HF + c]);
        atomicAdd(&psum[c], part);
    }
    __syncthreads();

    if (t < FDIM) {
        float s = (psum[t] + psum[t + FDIM]) * (1.f / (2 * NPG));
        out[(size_t)g * (3 * FDIM) + layer * FDIM + t] = leaky(s, 0.1f);
    }
}

extern "C" void kernel_launch(void* const* d_in, const int* in_sizes, int n_in,
                              void* d_out, int out_size, void* d_ws, size_t ws_size,
                              hipStream_t stream) {
    const float* x   = (const float*)d_in[0];
    const float* W0  = (const float*)d_in[1];
    const float* al0 = (const float*)d_in[2];
    const float* ar0 = (const float*)d_in[3];
    const float* rW0 = (const float*)d_in[4];
    const float* g0  = (const float*)d_in[5];
    const float* b0  = (const float*)d_in[6];
    const float* W1  = (const float*)d_in[7];
    const float* al1 = (const float*)d_in[8];
    const float* ar1 = (const float*)d_in[9];
    const float* g1  = (const float*)d_in[10];
    const float* b1  = (const float*)d_in[11];
    const float* W2  = (const float*)d_in[12];
    const float* al2 = (const float*)d_in[13];
    const float* ar2 = (const float*)d_in[14];
    const float* g2  = (const float*)d_in[15];
    const float* b2  = (const float*)d_in[16];
    const int* src   = (const int*)d_in[17];
    const int* dst   = (const int*)d_in[18];
    float* out = (float*)d_out;

    char* ws = (char*)d_ws;
    unsigned short* bufA = (unsigned short*)ws;                       // h1 [N,128] bf16
    unsigned short* bufB = bufA + (size_t)NNODES * HF;                // h2 [N,128] bf16
    unsigned short* wt0  = bufB + (size_t)NNODES * HF;
    unsigned short* wt1  = wt0 + 256 * 64;
    unsigned short* wt2  = wt1 + 128 * 128;

    prep_w<<<64, 256, 0, stream>>>(W0, rW0, W1, W2, wt0, wt1, wt2);

    layer_kernel<64, true, true><<<NGRAPH, 512, 0, stream>>>(
        x, wt0, al0, ar0, g0, b0, src, dst, bufA, out, 0);
    layer_kernel<128, false, true><<<NGRAPH, 512, 0, stream>>>(
        bufA, wt1, al1, ar1, g1, b1, src, dst, bufB, out, 1);
    layer_kernel<128, false, false><<<NGRAPH, 512, 0, stream>>>(
        bufB, wt2, al2, ar2, g2, b2, src, dst, nullptr, out, 2);
}

// Round 8
// 282.146 us; speedup vs baseline: 1.1951x; 1.1125x over previous
//
#include <hip/hip_runtime.h>

#define NPG    50
#define HF     128
#define FDIM   64
#define NGRAPH 2048
#define NNODES 102400
#define EPG    400
#define SP     72     // featT row stride (bf16): 144B, 16B-aligned
#define CS4    13     // cnt row stride (ints): 4 8-bit counts per int
#define HB     136    // hbuf row stride (bf16): 272B, 16B-aligned

typedef __attribute__((ext_vector_type(8))) short bf16x8;
typedef __attribute__((ext_vector_type(4))) float floatx4;

__device__ __forceinline__ float leaky(float x, float s) { return x >= 0.f ? x : x * s; }
__device__ __forceinline__ unsigned short f2bf(float f) {   // RNE fp32->bf16
    unsigned u = __float_as_uint(f);
    return (unsigned short)((u + 0x7fffu + ((u >> 16) & 1u)) >> 16);
}
__device__ __forceinline__ float bf2f(unsigned short h) {
    return __uint_as_float(((unsigned)h) << 16);
}
__device__ __forceinline__ int fkey(float f) { int b = __float_as_int(f); return b >= 0 ? b : b ^ 0x7fffffff; }
__device__ __forceinline__ float funkey(int k) { return __int_as_float(k >= 0 ? k : k ^ 0x7fffffff); }

// Build transposed bf16 weights: wt0[256][64] = [W0|resW0]^T, wt1/wt2[128][128] = W^T
__global__ void prep_w(const float* __restrict__ W0, const float* __restrict__ rW0,
                       const float* __restrict__ W1, const float* __restrict__ W2,
                       unsigned short* __restrict__ wt0, unsigned short* __restrict__ wt1,
                       unsigned short* __restrict__ wt2) {
    int i = blockIdx.x * 256 + threadIdx.x;
    if (i < 256 * 64) {
        int n = i >> 6, k = i & 63;
        float v = (n < 128) ? W0[k * 128 + n] : rW0[k * 128 + (n - 128)];
        wt0[i] = f2bf(v);
    }
    if (i < 128 * 128) {
        int n = i >> 7, k = i & 127;
        wt1[i] = f2bf(W1[k * 128 + n]);
        wt2[i] = f2bf(W2[k * 128 + n]);
    }
}

// RESW (layer0): hin is fp32 [N,64]; else hin is packed bf16 [N,128].
// launch_bounds (512,6): 85-VGPR cap -- (512,8)'s 64-VGPR cap forced scratch
// spills (R7: +160 MB/dispatch HBM).  3 blocks/CU via VGPR, LDS 38.4 KB.
template <int K, bool RESW, bool WRITE_H>
__global__ __launch_bounds__(512, 6) void layer_kernel(
    const void* __restrict__ hin_, const unsigned short* __restrict__ Wt,
    const float* __restrict__ al, const float* __restrict__ ar,
    const float* __restrict__ gw, const float* __restrict__ bw,
    const int* __restrict__ src, const int* __restrict__ dst,
    unsigned short* __restrict__ hout, float* __restrict__ out, int layer)
{
    __shared__ unsigned short featT[HF * SP];       // 18432 B; reused as ybuf[50][128]
    __shared__ int cnt[NPG * CS4];                  // 2600 B
    __shared__ unsigned short hres[NPG * HB];       // 13600 B: L0 res_b[50][128]; L1/2 hbuf[50][HB]
    __shared__ float el_s[128], er_s[128], rden_s[128];
    __shared__ int elmax_i[2];
    __shared__ float musum[64], sqsum[64], psum[HF], gb_s[2 * HF];

    const float* hinf = (const float*)hin_;
    const unsigned short* hinb = (const unsigned short*)hin_;
    unsigned short* ybuf = featT;   // alias: featT dead after aggregation MFMA

    const int g = blockIdx.x, t = threadIdx.x;
    const int nbase = g * NPG;
    const int w = t >> 6, lane = t & 63, quad = lane >> 4, l16 = lane & 15;

    // early edge loads
    int es = 0, ed = 0;
    if (t < EPG) { es = src[g * EPG + t] - nbase; ed = dst[g * EPG + t] - nbase; }

    // ---- P0: zero / stage ----
    for (int i = t; i < NPG * CS4; i += 512) cnt[i] = 0;
    if (t < 64) { musum[t] = 0.f; sqsum[t] = 0.f; }
    if (t < HF) { psum[t] = 0.f; gb_s[t] = gw[t]; gb_s[HF + t] = bw[t]; }
    if (t < 2) elmax_i[t] = (int)0x80000000;
    if constexpr (!RESW) {   // stage h block (bf16) into hbuf, coalesced
        for (int i = t; i < 800; i += 512) {
            int row = i >> 4, c = i & 15;
            *(uint4*)&hres[row * HB + c * 8] =
                *(const uint4*)&hinb[(size_t)(nbase + row) * HF + c * 8];
        }
    }
    __syncthreads();

    if (t < EPG) atomicAdd(&cnt[ed * CS4 + (es >> 2)], 1 << ((es & 3) * 8));
    if (t < NPG) atomicAdd(&cnt[t * CS4 + (t >> 2)], 1 << ((t & 3) * 8));

    // ---- P1: GEMM via MFMA + el/er + elmax + featT/res stores ----
    constexpr int KS = K / 32;
    constexpr int NT = RESW ? 8 : 4;
    const int mt = w & 3;
    const int ntbase = (w >> 2) * NT;

    int mrow = mt * 16 + l16;
    if (mrow >= NPG) mrow = NPG - 1;
    bf16x8 afr[KS];
    if constexpr (RESW) {
        const float* hrow = hinf + (size_t)(nbase + mrow) * K;
#pragma unroll
        for (int ks = 0; ks < KS; ++ks) {
            int k0 = ks * 32 + quad * 8;
            float4 p0 = *(const float4*)(hrow + k0);
            float4 p1 = *(const float4*)(hrow + k0 + 4);
            bf16x8 a;
            a[0] = (short)f2bf(p0.x); a[1] = (short)f2bf(p0.y);
            a[2] = (short)f2bf(p0.z); a[3] = (short)f2bf(p0.w);
            a[4] = (short)f2bf(p1.x); a[5] = (short)f2bf(p1.y);
            a[6] = (short)f2bf(p1.z); a[7] = (short)f2bf(p1.w);
            afr[ks] = a;
        }
    } else {
#pragma unroll
        for (int ks = 0; ks < KS; ++ks)
            afr[ks] = *(const bf16x8*)&hres[mrow * HB + ks * 32 + quad * 8];
    }

    floatx4 acc[NT];
    const floatx4 zf = {0.f, 0.f, 0.f, 0.f};
#pragma unroll
    for (int nt = 0; nt < NT; ++nt) acc[nt] = zf;
#pragma unroll
    for (int nt = 0; nt < NT; ++nt) {
        const unsigned short* wrow = Wt + (size_t)((ntbase + nt) * 16 + l16) * K;
#pragma unroll
        for (int ks = 0; ks < KS; ++ks) {
            bf16x8 b = *(const bf16x8*)(wrow + ks * 32 + quad * 8);
            acc[nt] = __builtin_amdgcn_mfma_f32_16x16x32_bf16(afr[ks], b, acc[nt], 0, 0, 0);
        }
    }

    // el/er from fp32 acc: butterfly over l16 lanes; elmax via LDS atomicMax.
    if (!RESW || w < 4) {
        float pe0[4] = {0,0,0,0}, pr0[4] = {0,0,0,0};
        float pe1[4] = {0,0,0,0}, pr1[4] = {0,0,0,0};
#pragma unroll
        for (int nt = 0; nt < NT; ++nt) {
            int col = (ntbase + nt) * 16 + l16;
            if (RESW && col >= HF) continue;
            float av = al[col], rv = ar[col];
            bool second = RESW && (nt >= 4);
#pragma unroll
            for (int r = 0; r < 4; ++r) {
                float x = acc[nt][r];
                if (second) { pe1[r] = fmaf(x, av, pe1[r]); pr1[r] = fmaf(x, rv, pr1[r]); }
                else        { pe0[r] = fmaf(x, av, pe0[r]); pr0[r] = fmaf(x, rv, pr0[r]); }
            }
        }
#pragma unroll
        for (int m = 1; m <= 8; m <<= 1) {
#pragma unroll
            for (int r = 0; r < 4; ++r) {
                pe0[r] += __shfl_xor(pe0[r], m, 64);
                pr0[r] += __shfl_xor(pr0[r], m, 64);
                if (RESW) { pe1[r] += __shfl_xor(pe1[r], m, 64);
                            pr1[r] += __shfl_xor(pr1[r], m, 64); }
            }
        }
        if (l16 == 0) {
#pragma unroll
            for (int r = 0; r < 4; ++r) {
                int row = mt * 16 + quad * 4 + r;
                if (RESW) {
                    el_s[row] = pe0[r];      er_s[row] = pr0[r];
                    el_s[64 + row] = pe1[r]; er_s[64 + row] = pr1[r];
                    atomicMax(&elmax_i[0], fkey(pe0[r]));
                    atomicMax(&elmax_i[1], fkey(pe1[r]));
                } else {
                    int hd = w >> 2;
                    el_s[hd * 64 + row] = pe0[r];
                    er_s[hd * 64 + row] = pr0[r];
                    atomicMax(&elmax_i[hd], fkey(pe0[r]));
                }
            }
        }
    }

    // featT stores (b64-packed) / res stores bf16 (L0 high cols, stride 128)
#pragma unroll
    for (int nt = 0; nt < NT; ++nt) {
        int n = (ntbase + nt) * 16 + l16;
        if (!RESW || n < HF) {
            unsigned lo = (unsigned)f2bf(acc[nt][0]) | ((unsigned)f2bf(acc[nt][1]) << 16);
            unsigned hi = (unsigned)f2bf(acc[nt][2]) | ((unsigned)f2bf(acc[nt][3]) << 16);
            uint2 pk = {lo, hi};
            *(uint2*)&featT[n * SP + mt * 16 + quad * 4] = pk;
        } else {
#pragma unroll
            for (int r = 0; r < 4; ++r) {
                int d = mt * 16 + quad * 4 + r;
                if (d < NPG) hres[d * HF + (n - HF)] = f2bf(acc[nt][r]);
            }
        }
    }
    __syncthreads();

    // ---- P3: A-frag exp build + aggregation MFMA + LN stats ----
    const int hd = w >> 2, amt = w & 3;
    const int d = amt * 16 + l16;   // this lane's A-frag dst row

    float erd = (d < NPG) ? er_s[hd * 64 + d] : 0.f;
    float md = leaky(funkey(elmax_i[hd]) + erd, 0.2f);
    bf16x8 ap[2];
    float rowsum = 0.f;
#pragma unroll
    for (int ks = 0; ks < 2; ++ks) {
        bf16x8 a;
#pragma unroll
        for (int j = 0; j < 8; ++j) {
            int s = ks * 32 + quad * 8 + j;
            float x = 0.f;
            if (d < NPG && s < NPG) {
                int c = (cnt[d * CS4 + (s >> 2)] >> ((s & 3) * 8)) & 0xff;
                if (c) x = (float)c * __expf(leaky(el_s[hd * 64 + s] + erd, 0.2f) - md);
            }
            unsigned short xb = f2bf(x);
            a[j] = (short)xb;
            rowsum += bf2f(xb);
        }
        ap[ks] = a;
    }
    rowsum += __shfl_xor(rowsum, 16, 64);
    rowsum += __shfl_xor(rowsum, 32, 64);
    if (quad == 0) rden_s[hd * 64 + d] = 1.f / fmaxf(rowsum, 1e-30f);

    floatx4 ag[4];
#pragma unroll
    for (int nt = 0; nt < 4; ++nt) ag[nt] = zf;
#pragma unroll
    for (int nt = 0; nt < 4; ++nt) {
        const unsigned short* fr = &featT[(hd * 64 + nt * 16 + l16) * SP];
#pragma unroll
        for (int ks = 0; ks < 2; ++ks) {
            bf16x8 b = *(const bf16x8*)(fr + ks * 32 + quad * 8);
            ag[nt] = __builtin_amdgcn_mfma_f32_16x16x32_bf16(ap[ks], b, ag[nt], 0, 0, 0);
        }
    }

    // scale + residual (from LDS: L0 res_b stride HF, L1/2 hbuf stride HB); LN partials
    float vals[4][4];
    float s1[4] = {0,0,0,0}, s2[4] = {0,0,0,0};
#pragma unroll
    for (int nt = 0; nt < 4; ++nt) {
#pragma unroll
        for (int r = 0; r < 4; ++r) {
            int dd = amt * 16 + quad * 4 + r;
            float rdv = rden_s[hd * 64 + (dd < 64 ? dd : 63)];
            int col = hd * 64 + nt * 16 + l16;
            int dc = dd < NPG ? dd : NPG - 1;
            float rv = RESW ? bf2f(hres[dc * HF + col]) : bf2f(hres[dc * HB + col]);
            float vv = ag[nt][r] * rdv + rv;
            vals[nt][r] = vv;
            s1[r] += vv;
            s2[r] = fmaf(vv, vv, s2[r]);
        }
    }
#pragma unroll
    for (int m = 1; m <= 8; m <<= 1) {
#pragma unroll
        for (int r = 0; r < 4; ++r) {
            s1[r] += __shfl_xor(s1[r], m, 64);
            s2[r] += __shfl_xor(s2[r], m, 64);
        }
    }
    if (l16 == 0) {
#pragma unroll
        for (int r = 0; r < 4; ++r) {
            int dd = amt * 16 + quad * 4 + r;
            if (dd < NPG) { atomicAdd(&musum[dd], s1[r]); atomicAdd(&sqsum[dd], s2[r]); }
        }
    }
    __syncthreads();   // LN stats complete; featT reads complete -> ybuf may overwrite

    // normalize + affine + leaky from registers -> ybuf (bf16, hout image)
#pragma unroll
    for (int nt = 0; nt < 4; ++nt) {
        int col = hd * 64 + nt * 16 + l16;
        float gq = gb_s[col], bq = gb_s[HF + col];
#pragma unroll
        for (int r = 0; r < 4; ++r) {
            int dd = amt * 16 + quad * 4 + r;
            if (dd < NPG) {
                float mu = musum[dd] * (1.f / HF);
                float rs = rsqrtf(sqsum[dd] * (1.f / HF) - mu * mu + 1e-5f);
                float y = (vals[nt][r] - mu) * rs * gq + bq;
                ybuf[dd * HF + col] = f2bf(leaky(y, 0.1f));
            }
        }
    }
    __syncthreads();

    // ---- P4: coalesced h store + readout ----
    if constexpr (WRITE_H) {
        for (int i = t; i < 800; i += 512)
            *(uint4*)&hout[(size_t)nbase * HF + i * 8] = *(const uint4*)&ybuf[i * 8];
    }
    {
        const int c = t & 127, g4 = t >> 7;
        float part = 0.f;
        for (int n = g4; n < NPG; n += 4) part += bf2f(ybuf[n * HF + c]);
        atomicAdd(&psum[c], part);
    }
    __syncthreads();

    if (t < FDIM) {
        float s = (psum[t] + psum[t + FDIM]) * (1.f / (2 * NPG));
        out[(size_t)g * (3 * FDIM) + layer * FDIM + t] = leaky(s, 0.1f);
    }
}

extern "C" void kernel_launch(void* const* d_in, const int* in_sizes, int n_in,
                              void* d_out, int out_size, void* d_ws, size_t ws_size,
                              hipStream_t stream) {
    const float* x   = (const float*)d_in[0];
    const float* W0  = (const float*)d_in[1];
    const float* al0 = (const float*)d_in[2];
    const float* ar0 = (const float*)d_in[3];
    const float* rW0 = (const float*)d_in[4];
    const float* g0  = (const float*)d_in[5];
    const float* b0  = (const float*)d_in[6];
    const float* W1  = (const float*)d_in[7];
    const float* al1 = (const float*)d_in[8];
    const float* ar1 = (const float*)d_in[9];
    const float* g1  = (const float*)d_in[10];
    const float* b1  = (const float*)d_in[11];
    const float* W2  = (const float*)d_in[12];
    const float* al2 = (const float*)d_in[13];
    const float* ar2 = (const float*)d_in[14];
    const float* g2  = (const float*)d_in[15];
    const float* b2  = (const float*)d_in[16];
    const int* src   = (const int*)d_in[17];
    const int* dst   = (const int*)d_in[18];
    float* out = (float*)d_out;

    char* ws = (char*)d_ws;
    unsigned short* bufA = (unsigned short*)ws;                       // h1 [N,128] bf16
    unsigned short* bufB = bufA + (size_t)NNODES * HF;                // h2 [N,128] bf16
    unsigned short* wt0  = bufB + (size_t)NNODES * HF;
    unsigned short* wt1  = wt0 + 256 * 64;
    unsigned short* wt2  = wt1 + 128 * 128;

    prep_w<<<64, 256, 0, stream>>>(W0, rW0, W1, W2, wt0, wt1, wt2);

    layer_kernel<64, true, true><<<NGRAPH, 512, 0, stream>>>(
        x, wt0, al0, ar0, g0, b0, src, dst, bufA, out, 0);
    layer_kernel<128, false, true><<<NGRAPH, 512, 0, stream>>>(
        bufA, wt1, al1, ar1, g1, b1, src, dst, bufB, out, 1);
    layer_kernel<128, false, false><<<NGRAPH, 512, 0, stream>>>(
        bufB, wt2, al2, ar2, g2, b2, src, dst, nullptr, out, 2);
}

// Round 9
// 269.450 us; speedup vs baseline: 1.2514x; 1.0471x over previous
//
#include <hip/hip_runtime.h>

#define NPG    50
#define HF     128
#define FDIM   64
#define NGRAPH 2048
#define NNODES 102400
#define EPG    400
#define SP     72     // featT row stride (bf16): 144B, 16B-aligned
#define CSI    36     // cnt row stride (ints): 16B-aligned rows, 2 counts/int
#define HB     136    // L0 res row stride (bf16)

typedef __attribute__((ext_vector_type(8))) short bf16x8;
typedef __attribute__((ext_vector_type(4))) float floatx4;

__device__ __forceinline__ float leaky(float x, float s) { return x >= 0.f ? x : x * s; }
__device__ __forceinline__ unsigned short f2bf(float f) {   // RNE fp32->bf16
    unsigned u = __float_as_uint(f);
    return (unsigned short)((u + 0x7fffu + ((u >> 16) & 1u)) >> 16);
}
__device__ __forceinline__ float bf2f(unsigned short h) {
    return __uint_as_float(((unsigned)h) << 16);
}

// Build transposed bf16 weights: wt0[256][64] = [W0|resW0]^T, wt1/wt2[128][128] = W^T
__global__ void prep_w(const float* __restrict__ W0, const float* __restrict__ rW0,
                       const float* __restrict__ W1, const float* __restrict__ W2,
                       unsigned short* __restrict__ wt0, unsigned short* __restrict__ wt1,
                       unsigned short* __restrict__ wt2) {
    int i = blockIdx.x * 256 + threadIdx.x;
    if (i < 256 * 64) {
        int n = i >> 6, k = i & 63;
        float v = (n < 128) ? W0[k * 128 + n] : rW0[k * 128 + (n - 128)];
        wt0[i] = f2bf(v);
    }
    if (i < 128 * 128) {
        int n = i >> 7, k = i & 127;
        wt1[i] = f2bf(W1[k * 128 + n]);
        wt2[i] = f2bf(W2[k * 128 + n]);
    }
}

// RESW (layer0): hin fp32 [N,64]; else hin packed bf16 [N,128].
// (512,6): 64-reg cap of (512,8) spilled (R7, +160MB HBM); combined VGPR+AGPR
// ~88 -> ~2.5 blocks/CU regardless, so optimize critical path not occupancy.
template <int K, bool RESW, bool WRITE_H>
__global__ __launch_bounds__(512, 6) void layer_kernel(
    const void* __restrict__ hin_, const unsigned short* __restrict__ Wt,
    const float* __restrict__ al, const float* __restrict__ ar,
    const float* __restrict__ gw, const float* __restrict__ bw,
    const int* __restrict__ src, const int* __restrict__ dst,
    unsigned short* __restrict__ hout, float* __restrict__ out, int layer)
{
    __shared__ unsigned short featT[HF * SP];       // 18432 B; reused as ybuf[50][128]
    __shared__ int cnt[64 * CSI];                   // 9216 B, rows 50..63 stay zero
    __shared__ unsigned short res_s[RESW ? NPG * HB : 1];  // 13600 B, L0 only
    __shared__ float el_s[128], er_s[128], rden_s[128];
    __shared__ float musum[64], sqsum[64], psum[HF], gb_s[2 * HF];

    const float* hinf = (const float*)hin_;
    const unsigned short* hinb = (const unsigned short*)hin_;
    unsigned short* ybuf = featT;   // alias: featT dead after aggregation MFMA

    const int g = blockIdx.x, t = threadIdx.x;
    const int nbase = g * NPG;
    const int w = t >> 6, lane = t & 63, quad = lane >> 4, l16 = lane & 15;

    // ---- issue independent global loads at cycle 0 ----
    int es = 0, ed = 0;
    if (t < EPG) { es = src[g * EPG + t] - nbase; ed = dst[g * EPG + t] - nbase; }

    constexpr int KS = K / 32;
    constexpr int NT = RESW ? 8 : 4;
    const int mt = w & 3;
    const int ntbase = (w >> 2) * NT;
    int mrow = mt * 16 + l16;
    if (mrow >= NPG) mrow = NPG - 1;

    bf16x8 afr[KS];
    if constexpr (RESW) {
        const float* hrow = hinf + (size_t)(nbase + mrow) * K;
#pragma unroll
        for (int ks = 0; ks < KS; ++ks) {
            int k0 = ks * 32 + quad * 8;
            float4 p0 = *(const float4*)(hrow + k0);
            float4 p1 = *(const float4*)(hrow + k0 + 4);
            bf16x8 a;
            a[0] = (short)f2bf(p0.x); a[1] = (short)f2bf(p0.y);
            a[2] = (short)f2bf(p0.z); a[3] = (short)f2bf(p0.w);
            a[4] = (short)f2bf(p1.x); a[5] = (short)f2bf(p1.y);
            a[6] = (short)f2bf(p1.z); a[7] = (short)f2bf(p1.w);
            afr[ks] = a;
        }
    } else {
        const unsigned short* hrow = hinb + (size_t)(nbase + mrow) * K;
#pragma unroll
        for (int ks = 0; ks < KS; ++ks)
            afr[ks] = *(const bf16x8*)(hrow + ks * 32 + quad * 8);
    }

    // ---- P0: zero ----
    for (int i = t; i < 64 * CSI; i += 512) cnt[i] = 0;
    if (t < 64) { musum[t] = 0.f; sqsum[t] = 0.f; }
    if (t < HF) { psum[t] = 0.f; gb_s[t] = gw[t]; gb_s[HF + t] = bw[t]; }
    __syncthreads();

    if (t < EPG) atomicAdd(&cnt[ed * CSI + (es >> 1)], 1 << ((es & 1) * 16));
    if (t < NPG) atomicAdd(&cnt[t * CSI + (t >> 1)], 1 << ((t & 1) * 16));

    // ---- P1: GEMM via MFMA + el/er + featT/res stores ----
    floatx4 acc[NT];
    const floatx4 zf = {0.f, 0.f, 0.f, 0.f};
#pragma unroll
    for (int nt = 0; nt < NT; ++nt) acc[nt] = zf;
#pragma unroll
    for (int nt = 0; nt < NT; ++nt) {
        const unsigned short* wrow = Wt + (size_t)((ntbase + nt) * 16 + l16) * K;
#pragma unroll
        for (int ks = 0; ks < KS; ++ks) {
            bf16x8 b = *(const bf16x8*)(wrow + ks * 32 + quad * 8);
            acc[nt] = __builtin_amdgcn_mfma_f32_16x16x32_bf16(afr[ks], b, acc[nt], 0, 0, 0);
        }
    }

    // el/er from fp32 acc: butterfly over l16 lanes.
    if (!RESW || w < 4) {
        float pe0[4] = {0,0,0,0}, pr0[4] = {0,0,0,0};
        float pe1[4] = {0,0,0,0}, pr1[4] = {0,0,0,0};
#pragma unroll
        for (int nt = 0; nt < NT; ++nt) {
            int col = (ntbase + nt) * 16 + l16;
            if (RESW && col >= HF) continue;
            float av = al[col], rv = ar[col];
            bool second = RESW && (nt >= 4);
#pragma unroll
            for (int r = 0; r < 4; ++r) {
                float x = acc[nt][r];
                if (second) { pe1[r] = fmaf(x, av, pe1[r]); pr1[r] = fmaf(x, rv, pr1[r]); }
                else        { pe0[r] = fmaf(x, av, pe0[r]); pr0[r] = fmaf(x, rv, pr0[r]); }
            }
        }
#pragma unroll
        for (int m = 1; m <= 8; m <<= 1) {
#pragma unroll
            for (int r = 0; r < 4; ++r) {
                pe0[r] += __shfl_xor(pe0[r], m, 64);
                pr0[r] += __shfl_xor(pr0[r], m, 64);
                if (RESW) { pe1[r] += __shfl_xor(pe1[r], m, 64);
                            pr1[r] += __shfl_xor(pr1[r], m, 64); }
            }
        }
        if (l16 == 0) {
#pragma unroll
            for (int r = 0; r < 4; ++r) {
                int row = mt * 16 + quad * 4 + r;
                if (RESW) {
                    el_s[row] = pe0[r];      er_s[row] = pr0[r];
                    el_s[64 + row] = pe1[r]; er_s[64 + row] = pr1[r];
                } else {
                    int hd = w >> 2;
                    el_s[hd * 64 + row] = pe0[r];
                    er_s[hd * 64 + row] = pr0[r];
                }
            }
        }
    }

    // featT stores (b64-packed) / L0 res stores bf16
#pragma unroll
    for (int nt = 0; nt < NT; ++nt) {
        int n = (ntbase + nt) * 16 + l16;
        if (!RESW || n < HF) {
            unsigned lo = (unsigned)f2bf(acc[nt][0]) | ((unsigned)f2bf(acc[nt][1]) << 16);
            unsigned hi = (unsigned)f2bf(acc[nt][2]) | ((unsigned)f2bf(acc[nt][3]) << 16);
            uint2 pk = {lo, hi};
            *(uint2*)&featT[n * SP + mt * 16 + quad * 4] = pk;
        } else {
#pragma unroll
            for (int r = 0; r < 4; ++r) {
                int d = mt * 16 + quad * 4 + r;
                if (d < NPG) res_s[d * HB + (n - HF)] = f2bf(acc[nt][r]);
            }
        }
    }
    __syncthreads();

    // ---- P3: exp A-frag + aggregation MFMA + LN stats ----
    const int hd = w >> 2, amt = w & 3;
    const int d = amt * 16 + l16;   // this lane's A-frag dst row (may be >=NPG: cnt row zero)

    // residual prefetch (L1/2): issue early, consumed post-MFMA
    float resid[4][4];
    if (!RESW) {
#pragma unroll
        for (int nt = 0; nt < 4; ++nt)
#pragma unroll
            for (int r = 0; r < 4; ++r) {
                int dd = amt * 16 + quad * 4 + r;
                if (dd >= NPG) dd = NPG - 1;
                resid[nt][r] = bf2f(hinb[(size_t)(nbase + dd) * K + hd * 64 + nt * 16 + l16]);
            }
    }

    // no max-shift: |el+er| bounded (~12) -> exp safe in fp32; softmax shift-invariant
    const float erd = er_s[hd * 64 + (d < 64 ? d : 63)];
    float elv[16];
    *(float4*)&elv[0]  = *(const float4*)&el_s[hd * 64 + quad * 8];
    *(float4*)&elv[4]  = *(const float4*)&el_s[hd * 64 + quad * 8 + 4];
    *(float4*)&elv[8]  = *(const float4*)&el_s[hd * 64 + 32 + quad * 8];
    *(float4*)&elv[12] = *(const float4*)&el_s[hd * 64 + 32 + quad * 8 + 4];
    int4 ci0 = *(const int4*)&cnt[d * CSI + quad * 4];
    int4 ci1 = *(const int4*)&cnt[d * CSI + 16 + quad * 4];

    bf16x8 ap[2];
    float rowsum = 0.f;
#pragma unroll
    for (int ks = 0; ks < 2; ++ks) {
        const int* ci = ks ? (const int*)&ci1 : (const int*)&ci0;
        bf16x8 a;
#pragma unroll
        for (int j = 0; j < 8; ++j) {
            float x = elv[ks * 8 + j] + erd;
            x = fmaxf(x, 0.2f * x);                       // leaky, slope<1
            float p = __expf(x);
            int c = (ci[j >> 1] >> ((j & 1) * 16)) & 0xffff;
            unsigned short xb = f2bf((float)c * p);       // c==0 -> exact 0
            a[j] = (short)xb;
            rowsum += bf2f(xb);
        }
        ap[ks] = a;
    }
    rowsum += __shfl_xor(rowsum, 16, 64);
    rowsum += __shfl_xor(rowsum, 32, 64);
    if (quad == 0 && d < 64) rden_s[hd * 64 + d] = 1.f / fmaxf(rowsum, 1e-30f);

    floatx4 ag[4];
#pragma unroll
    for (int nt = 0; nt < 4; ++nt) ag[nt] = zf;
#pragma unroll
    for (int nt = 0; nt < 4; ++nt) {
        const unsigned short* fr = &featT[(hd * 64 + nt * 16 + l16) * SP];
#pragma unroll
        for (int ks = 0; ks < 2; ++ks) {
            bf16x8 b = *(const bf16x8*)(fr + ks * 32 + quad * 8);
            ag[nt] = __builtin_amdgcn_mfma_f32_16x16x32_bf16(ap[ks], b, ag[nt], 0, 0, 0);
        }
    }

    // scale + residual; LN partial sums
    float vals[4][4];
    float s1[4] = {0,0,0,0}, s2[4] = {0,0,0,0};
#pragma unroll
    for (int r = 0; r < 4; ++r) {
        int dd = amt * 16 + quad * 4 + r;
        float rdv = rden_s[hd * 64 + (dd < 64 ? dd : 63)];
        int dc = dd < NPG ? dd : NPG - 1;
#pragma unroll
        for (int nt = 0; nt < 4; ++nt) {
            int col = hd * 64 + nt * 16 + l16;
            float rv = RESW ? bf2f(res_s[dc * HB + col]) : resid[nt][r];
            float vv = ag[nt][r] * rdv + rv;
            vals[nt][r] = vv;
            s1[r] += vv;
            s2[r] = fmaf(vv, vv, s2[r]);
        }
    }
#pragma unroll
    for (int m = 1; m <= 8; m <<= 1) {
#pragma unroll
        for (int r = 0; r < 4; ++r) {
            s1[r] += __shfl_xor(s1[r], m, 64);
            s2[r] += __shfl_xor(s2[r], m, 64);
        }
    }
    if (l16 == 0) {
#pragma unroll
        for (int r = 0; r < 4; ++r) {
            int dd = amt * 16 + quad * 4 + r;
            if (dd < NPG) { atomicAdd(&musum[dd], s1[r]); atomicAdd(&sqsum[dd], s2[r]); }
        }
    }
    __syncthreads();   // LN stats done; featT reads done -> ybuf may overwrite

    // normalize + affine + leaky from registers -> ybuf (bf16)
#pragma unroll
    for (int r = 0; r < 4; ++r) {
        int dd = amt * 16 + quad * 4 + r;
        if (dd < NPG) {
            float mu = musum[dd] * (1.f / HF);
            float rs = rsqrtf(sqsum[dd] * (1.f / HF) - mu * mu + 1e-5f);
#pragma unroll
            for (int nt = 0; nt < 4; ++nt) {
                int col = hd * 64 + nt * 16 + l16;
                float y = (vals[nt][r] - mu) * rs * gb_s[col] + gb_s[HF + col];
                ybuf[dd * HF + col] = f2bf(leaky(y, 0.1f));
            }
        }
    }
    __syncthreads();

    // ---- P4: coalesced h store + readout ----
    if constexpr (WRITE_H) {
        for (int i = t; i < 800; i += 512)
            *(uint4*)&hout[(size_t)nbase * HF + i * 8] = *(const uint4*)&ybuf[i * 8];
    }
    {
        const int c = t & 127, g4 = t >> 7;
        float part = 0.f;
        for (int n = g4; n < NPG; n += 4) part += bf2f(ybuf[n * HF + c]);
        atomicAdd(&psum[c], part);
    }
    __syncthreads();

    if (t < FDIM) {
        float s = (psum[t] + psum[t + FDIM]) * (1.f / (2 * NPG));
        out[(size_t)g * (3 * FDIM) + layer * FDIM + t] = leaky(s, 0.1f);
    }
}

extern "C" void kernel_launch(void* const* d_in, const int* in_sizes, int n_in,
                              void* d_out, int out_size, void* d_ws, size_t ws_size,
                              hipStream_t stream) {
    const float* x   = (const float*)d_in[0];
    const float* W0  = (const float*)d_in[1];
    const float* al0 = (const float*)d_in[2];
    const float* ar0 = (const float*)d_in[3];
    const float* rW0 = (const float*)d_in[4];
    const float* g0  = (const float*)d_in[5];
    const float* b0  = (const float*)d_in[6];
    const float* W1  = (const float*)d_in[7];
    const float* al1 = (const float*)d_in[8];
    const float* ar1 = (const float*)d_in[9];
    const float* g1  = (const float*)d_in[10];
    const float* b1  = (const float*)d_in[11];
    const float* W2  = (const float*)d_in[12];
    const float* al2 = (const float*)d_in[13];
    const float* ar2 = (const float*)d_in[14];
    const float* g2  = (const float*)d_in[15];
    const float* b2  = (const float*)d_in[16];
    const int* src   = (const int*)d_in[17];
    const int* dst   = (const int*)d_in[18];
    float* out = (float*)d_out;

    char* ws = (char*)d_ws;
    unsigned short* bufA = (unsigned short*)ws;                       // h1 [N,128] bf16
    unsigned short* bufB = bufA + (size_t)NNODES * HF;                // h2 [N,128] bf16
    unsigned short* wt0  = bufB + (size_t)NNODES * HF;
    unsigned short* wt1  = wt0 + 256 * 64;
    unsigned short* wt2  = wt1 + 128 * 128;

    prep_w<<<64, 256, 0, stream>>>(W0, rW0, W1, W2, wt0, wt1, wt2);

    layer_kernel<64, true, true><<<NGRAPH, 512, 0, stream>>>(
        x, wt0, al0, ar0, g0, b0, src, dst, bufA, out, 0);
    layer_kernel<128, false, true><<<NGRAPH, 512, 0, stream>>>(
        bufA, wt1, al1, ar1, g1, b1, src, dst, bufB, out, 1);
    layer_kernel<128, false, false><<<NGRAPH, 512, 0, stream>>>(
        bufB, wt2, al2, ar2, g2, b2, src, dst, nullptr, out, 2);
}

// Round 10
// 256.874 us; speedup vs baseline: 1.3127x; 1.0490x over previous
//
#include <hip/hip_runtime.h>

#define NPG    50
#define HF     128
#define FDIM   64
#define NGRAPH 2048
#define NNODES 102400
#define EPG    400
#define SP     72     // featT row stride (bf16)
#define CSI    36     // cnt row stride (ints), 2 counts/int, 16B-aligned rows
#define HB     136    // hbuf row stride (bf16), 16B-aligned rows

typedef __attribute__((ext_vector_type(8))) short bf16x8;
typedef __attribute__((ext_vector_type(4))) float floatx4;

__device__ __forceinline__ float leaky(float x, float s) { return x >= 0.f ? x : x * s; }
__device__ __forceinline__ unsigned short f2bf(float f) {   // RNE fp32->bf16
    unsigned u = __float_as_uint(f);
    return (unsigned short)((u + 0x7fffu + ((u >> 16) & 1u)) >> 16);
}
__device__ __forceinline__ float bf2f(unsigned short h) {
    return __uint_as_float(((unsigned)h) << 16);
}

// Build transposed bf16 weights: wt0[256][64] = [W0|resW0]^T, wt1/wt2[128][128] = W^T
__global__ void prep_w(const float* __restrict__ W0, const float* __restrict__ rW0,
                       const float* __restrict__ W1, const float* __restrict__ W2,
                       unsigned short* __restrict__ wt0, unsigned short* __restrict__ wt1,
                       unsigned short* __restrict__ wt2) {
    int i = blockIdx.x * 256 + threadIdx.x;
    if (i < 256 * 64) {
        int n = i >> 6, k = i & 63;
        float v = (n < 128) ? W0[k * 128 + n] : rW0[k * 128 + (n - 128)];
        wt0[i] = f2bf(v);
    }
    if (i < 128 * 128) {
        int n = i >> 7, k = i & 127;
        wt1[i] = f2bf(W1[k * 128 + n]);
        wt2[i] = f2bf(W2[k * 128 + n]);
    }
}

// One GAT layer, fully in-block.  hbuf holds (RESW: x@resW0, else: input h) on
// entry to the epilogue, and holds this layer's output y on exit.
template <int K, bool RESW>
__device__ __forceinline__ void gat_layer(
    const bf16x8* afr_in,                       // RESW: preloaded A-frags
    const unsigned short* __restrict__ Wt,
    const float* __restrict__ al, const float* __restrict__ ar,
    const float* __restrict__ gbl,              // this layer's [g(128)|b(128)] in LDS
    float* __restrict__ out, int layer, int g, int t,
    unsigned short* featT, unsigned short* hbuf, int* cnt,
    float* el_s, float* er_s, float* rden_s,
    float* musum, float* sqsum, float* psum)
{
    const int w = t >> 6, lane = t & 63, quad = lane >> 4, l16 = lane & 15;
    constexpr int KS = K / 32;
    constexpr int NT = RESW ? 8 : 4;
    const int mt = w & 3;
    const int ntbase = (w >> 2) * NT;
    int mrow = mt * 16 + l16;
    if (mrow >= NPG) mrow = NPG - 1;

    // ---- A-fragments ----
    bf16x8 afr[KS];
    if constexpr (RESW) {
#pragma unroll
        for (int ks = 0; ks < KS; ++ks) afr[ks] = afr_in[ks];
    } else {
#pragma unroll
        for (int ks = 0; ks < KS; ++ks)
            afr[ks] = *(const bf16x8*)&hbuf[mrow * HB + ks * 32 + quad * 8];
    }

    // ---- GEMM via MFMA ----
    floatx4 acc[NT];
    const floatx4 zf = {0.f, 0.f, 0.f, 0.f};
#pragma unroll
    for (int nt = 0; nt < NT; ++nt) acc[nt] = zf;
#pragma unroll
    for (int nt = 0; nt < NT; ++nt) {
        const unsigned short* wrow = Wt + (size_t)((ntbase + nt) * 16 + l16) * K;
#pragma unroll
        for (int ks = 0; ks < KS; ++ks) {
            bf16x8 b = *(const bf16x8*)(wrow + ks * 32 + quad * 8);
            acc[nt] = __builtin_amdgcn_mfma_f32_16x16x32_bf16(afr[ks], b, acc[nt], 0, 0, 0);
        }
    }

    // ---- el/er from fp32 acc: butterfly over l16 lanes ----
    if (!RESW || w < 4) {
        float pe0[4] = {0,0,0,0}, pr0[4] = {0,0,0,0};
        float pe1[4] = {0,0,0,0}, pr1[4] = {0,0,0,0};
#pragma unroll
        for (int nt = 0; nt < NT; ++nt) {
            int col = (ntbase + nt) * 16 + l16;
            if (RESW && col >= HF) continue;
            float av = al[col], rv = ar[col];
            bool second = RESW && (nt >= 4);
#pragma unroll
            for (int r = 0; r < 4; ++r) {
                float x = acc[nt][r];
                if (second) { pe1[r] = fmaf(x, av, pe1[r]); pr1[r] = fmaf(x, rv, pr1[r]); }
                else        { pe0[r] = fmaf(x, av, pe0[r]); pr0[r] = fmaf(x, rv, pr0[r]); }
            }
        }
#pragma unroll
        for (int m = 1; m <= 8; m <<= 1) {
#pragma unroll
            for (int r = 0; r < 4; ++r) {
                pe0[r] += __shfl_xor(pe0[r], m, 64);
                pr0[r] += __shfl_xor(pr0[r], m, 64);
                if (RESW) { pe1[r] += __shfl_xor(pe1[r], m, 64);
                            pr1[r] += __shfl_xor(pr1[r], m, 64); }
            }
        }
        if (l16 == 0) {
#pragma unroll
            for (int r = 0; r < 4; ++r) {
                int row = mt * 16 + quad * 4 + r;
                if (RESW) {
                    el_s[row] = pe0[r];      er_s[row] = pr0[r];
                    el_s[64 + row] = pe1[r]; er_s[64 + row] = pr1[r];
                } else {
                    int hd = w >> 2;
                    el_s[hd * 64 + row] = pe0[r];
                    er_s[hd * 64 + row] = pr0[r];
                }
            }
        }
    }

    // featT stores (b64-packed) / L0: res cols -> hbuf bf16
#pragma unroll
    for (int nt = 0; nt < NT; ++nt) {
        int n = (ntbase + nt) * 16 + l16;
        if (!RESW || n < HF) {
            unsigned lo = (unsigned)f2bf(acc[nt][0]) | ((unsigned)f2bf(acc[nt][1]) << 16);
            unsigned hi = (unsigned)f2bf(acc[nt][2]) | ((unsigned)f2bf(acc[nt][3]) << 16);
            uint2 pk = {lo, hi};
            *(uint2*)&featT[n * SP + mt * 16 + quad * 4] = pk;
        } else {
#pragma unroll
            for (int r = 0; r < 4; ++r) {
                int d = mt * 16 + quad * 4 + r;
                if (d < NPG) hbuf[d * HB + (n - HF)] = f2bf(acc[nt][r]);
            }
        }
    }
    __syncthreads();

    // ---- exp A-frag + aggregation MFMA + epilogue ----
    const int hd = w >> 2, amt = w & 3;
    const int d = amt * 16 + l16;    // A-frag dst row (>=NPG rows: cnt is zero)

    // no max-shift: |el+er| bounded -> fp32 exp safe; softmax shift-invariant
    const float erd = er_s[hd * 64 + d];
    float elv[16];
    *(float4*)&elv[0]  = *(const float4*)&el_s[hd * 64 + quad * 8];
    *(float4*)&elv[4]  = *(const float4*)&el_s[hd * 64 + quad * 8 + 4];
    *(float4*)&elv[8]  = *(const float4*)&el_s[hd * 64 + 32 + quad * 8];
    *(float4*)&elv[12] = *(const float4*)&el_s[hd * 64 + 32 + quad * 8 + 4];
    int4 ci0 = *(const int4*)&cnt[d * CSI + quad * 4];
    int4 ci1 = *(const int4*)&cnt[d * CSI + 16 + quad * 4];

    bf16x8 ap[2];
    float rowsum = 0.f;
#pragma unroll
    for (int ks = 0; ks < 2; ++ks) {
        const int* ci = ks ? (const int*)&ci1 : (const int*)&ci0;
        bf16x8 a;
#pragma unroll
        for (int j = 0; j < 8; ++j) {
            float x = elv[ks * 8 + j] + erd;
            x = fmaxf(x, 0.2f * x);                 // leaky (slope < 1)
            float p = __expf(x);
            int c = (ci[j >> 1] >> ((j & 1) * 16)) & 0xffff;
            unsigned short xb = f2bf((float)c * p); // c==0 -> exact 0
            a[j] = (short)xb;
            rowsum += bf2f(xb);
        }
        ap[ks] = a;
    }
    rowsum += __shfl_xor(rowsum, 16, 64);
    rowsum += __shfl_xor(rowsum, 32, 64);
    if (quad == 0) rden_s[hd * 64 + d] = 1.f / fmaxf(rowsum, 1e-30f);

    floatx4 ag[4];
#pragma unroll
    for (int nt = 0; nt < 4; ++nt) ag[nt] = zf;
#pragma unroll
    for (int nt = 0; nt < 4; ++nt) {
        const unsigned short* fr = &featT[(hd * 64 + nt * 16 + l16) * SP];
#pragma unroll
        for (int ks = 0; ks < 2; ++ks) {
            bf16x8 b = *(const bf16x8*)(fr + ks * 32 + quad * 8);
            ag[nt] = __builtin_amdgcn_mfma_f32_16x16x32_bf16(ap[ks], b, ag[nt], 0, 0, 0);
        }
    }

    // scale + residual (hbuf: RESW->x@resW0, else input h); LN partial sums
    float vals[4][4];
    float s1[4] = {0,0,0,0}, s2[4] = {0,0,0,0};
#pragma unroll
    for (int r = 0; r < 4; ++r) {
        int dd = amt * 16 + quad * 4 + r;
        float rdv = rden_s[hd * 64 + (dd < 64 ? dd : 63)];
        int dc = dd < NPG ? dd : NPG - 1;
#pragma unroll
        for (int nt = 0; nt < 4; ++nt) {
            int col = hd * 64 + nt * 16 + l16;
            float vv = fmaf(ag[nt][r], rdv, bf2f(hbuf[dc * HB + col]));
            vals[nt][r] = vv;
            s1[r] += vv;
            s2[r] = fmaf(vv, vv, s2[r]);
        }
    }
#pragma unroll
    for (int m = 1; m <= 8; m <<= 1) {
#pragma unroll
        for (int r = 0; r < 4; ++r) {
            s1[r] += __shfl_xor(s1[r], m, 64);
            s2[r] += __shfl_xor(s2[r], m, 64);
        }
    }
    if (l16 == 0) {
#pragma unroll
        for (int r = 0; r < 4; ++r) {
            int dd = amt * 16 + quad * 4 + r;
            if (dd < NPG) { atomicAdd(&musum[dd], s1[r]); atomicAdd(&sqsum[dd], s2[r]); }
        }
    }
    __syncthreads();   // LN stats done; all hbuf/featT reads done

    // normalize + affine + leaky -> y into hbuf (next layer's input)
#pragma unroll
    for (int r = 0; r < 4; ++r) {
        int dd = amt * 16 + quad * 4 + r;
        if (dd < NPG) {
            float mu = musum[dd] * (1.f / HF);
            float rs = rsqrtf(sqsum[dd] * (1.f / HF) - mu * mu + 1e-5f);
#pragma unroll
            for (int nt = 0; nt < 4; ++nt) {
                int col = hd * 64 + nt * 16 + l16;
                float y = (vals[nt][r] - mu) * rs * gbl[col] + gbl[HF + col];
                hbuf[dd * HB + col] = f2bf(leaky(y, 0.1f));
            }
        }
    }
    __syncthreads();

    // readout partials; re-zero LN stats for next layer
    {
        const int c = t & 127, g4 = t >> 7;
        float part = 0.f;
        for (int n = g4; n < NPG; n += 4) part += bf2f(hbuf[n * HB + c]);
        atomicAdd(&psum[c], part);
    }
    if (t < 64) { musum[t] = 0.f; sqsum[t] = 0.f; }
    __syncthreads();

    if (t < FDIM) {
        float s = (psum[t] + psum[t + FDIM]) * (1.f / (2 * NPG));
        out[(size_t)g * (3 * FDIM) + layer * FDIM + t] = leaky(s, 0.1f);
        psum[t] = 0.f; psum[t + FDIM] = 0.f;   // ready for next layer
    }
}

// One block per graph runs all 3 layers (edges never cross graphs -> no grid
// sync needed; h carried in LDS, never touches HBM).
__global__ __launch_bounds__(512, 6) void gat3_kernel(
    const float* __restrict__ x,
    const unsigned short* __restrict__ wt0,
    const unsigned short* __restrict__ wt1,
    const unsigned short* __restrict__ wt2,
    const float* __restrict__ al0, const float* __restrict__ ar0,
    const float* __restrict__ al1, const float* __restrict__ ar1,
    const float* __restrict__ al2, const float* __restrict__ ar2,
    const float* __restrict__ g0, const float* __restrict__ b0,
    const float* __restrict__ g1, const float* __restrict__ b1,
    const float* __restrict__ g2, const float* __restrict__ b2,
    const int* __restrict__ src, const int* __restrict__ dst,
    float* __restrict__ out)
{
    __shared__ unsigned short featT[HF * SP];   // 18432 B
    __shared__ unsigned short hbuf[NPG * HB];   // 13600 B (res/h/y carrier)
    __shared__ int cnt[64 * CSI];               // 9216 B, rows 50..63 stay zero
    __shared__ float el_s[128], er_s[128], rden_s[128];
    __shared__ float musum[64], sqsum[64], psum[HF];
    __shared__ float gb_s[3 * 2 * HF];          // 3 layers x [g|b]

    const int g = blockIdx.x, t = threadIdx.x;
    const int nbase = g * NPG;
    const int w = t >> 6, lane = t & 63, quad = lane >> 4, l16 = lane & 15;

    // independent global loads at cycle 0
    int es = 0, ed = 0;
    if (t < EPG) { es = src[g * EPG + t] - nbase; ed = dst[g * EPG + t] - nbase; }

    // L0 A-fragments from global fp32 x (early issue)
    const int mt = w & 3;
    int mrow = mt * 16 + l16;
    if (mrow >= NPG) mrow = NPG - 1;
    bf16x8 afr0[2];
    {
        const float* hrow = x + (size_t)(nbase + mrow) * 64;
#pragma unroll
        for (int ks = 0; ks < 2; ++ks) {
            int k0 = ks * 32 + quad * 8;
            float4 p0 = *(const float4*)(hrow + k0);
            float4 p1 = *(const float4*)(hrow + k0 + 4);
            bf16x8 a;
            a[0] = (short)f2bf(p0.x); a[1] = (short)f2bf(p0.y);
            a[2] = (short)f2bf(p0.z); a[3] = (short)f2bf(p0.w);
            a[4] = (short)f2bf(p1.x); a[5] = (short)f2bf(p1.y);
            a[6] = (short)f2bf(p1.z); a[7] = (short)f2bf(p1.w);
            afr0[ks] = a;
        }
    }

    // init
    for (int i = t; i < 64 * CSI; i += 512) cnt[i] = 0;
    if (t < 64) { musum[t] = 0.f; sqsum[t] = 0.f; }
    if (t < HF) {
        psum[t] = 0.f;
        gb_s[t] = g0[t];       gb_s[HF + t] = b0[t];
        gb_s[256 + t] = g1[t]; gb_s[256 + HF + t] = b1[t];
        gb_s[512 + t] = g2[t]; gb_s[512 + HF + t] = b2[t];
    }
    __syncthreads();

    // edge counts, once for all 3 layers (graph topology is layer-invariant)
    if (t < EPG) atomicAdd(&cnt[ed * CSI + (es >> 1)], 1 << ((es & 1) * 16));
    if (t < NPG) atomicAdd(&cnt[t * CSI + (t >> 1)], 1 << ((t & 1) * 16));

    gat_layer<64, true>(afr0, wt0, al0, ar0, &gb_s[0], out, 0, g, t,
                        featT, hbuf, cnt, el_s, er_s, rden_s, musum, sqsum, psum);
    gat_layer<128, false>(nullptr, wt1, al1, ar1, &gb_s[256], out, 1, g, t,
                          featT, hbuf, cnt, el_s, er_s, rden_s, musum, sqsum, psum);
    gat_layer<128, false>(nullptr, wt2, al2, ar2, &gb_s[512], out, 2, g, t,
                          featT, hbuf, cnt, el_s, er_s, rden_s, musum, sqsum, psum);
}

extern "C" void kernel_launch(void* const* d_in, const int* in_sizes, int n_in,
                              void* d_out, int out_size, void* d_ws, size_t ws_size,
                              hipStream_t stream) {
    const float* x   = (const float*)d_in[0];
    const float* W0  = (const float*)d_in[1];
    const float* al0 = (const float*)d_in[2];
    const float* ar0 = (const float*)d_in[3];
    const float* rW0 = (const float*)d_in[4];
    const float* g0  = (const float*)d_in[5];
    const float* b0  = (const float*)d_in[6];
    const float* W1  = (const float*)d_in[7];
    const float* al1 = (const float*)d_in[8];
    const float* ar1 = (const float*)d_in[9];
    const float* g1  = (const float*)d_in[10];
    const float* b1  = (const float*)d_in[11];
    const float* W2  = (const float*)d_in[12];
    const float* al2 = (const float*)d_in[13];
    const float* ar2 = (const float*)d_in[14];
    const float* g2  = (const float*)d_in[15];
    const float* b2  = (const float*)d_in[16];
    const int* src   = (const int*)d_in[17];
    const int* dst   = (const int*)d_in[18];
    float* out = (float*)d_out;

    unsigned short* wt0 = (unsigned short*)d_ws;
    unsigned short* wt1 = wt0 + 256 * 64;
    unsigned short* wt2 = wt1 + 128 * 128;

    prep_w<<<64, 256, 0, stream>>>(W0, rW0, W1, W2, wt0, wt1, wt2);
    gat3_kernel<<<NGRAPH, 512, 0, stream>>>(
        x, wt0, wt1, wt2, al0, ar0, al1, ar1, al2, ar2,
        g0, b0, g1, b1, g2, b2, src, dst, out);
}